// Round 7
// baseline (242.498 us; speedup 1.0000x reference)
//
#include <hip/hip_runtime.h>

// SNN IF scan, T=4. Memory-bound: 134 MB in + 134 MB out. Ladder:
// serialized loads = ~82 us; 16-deep nt burst = ~70; R6 32-deep nt u-major
// burst = ~62 (passing baseline); R7/R8/R9 schedule variants null at ~62.
// R10: caching loads -> kernel FETCH_SIZE halved (67 MB of x served from
// the 256 MiB memory-side Infinity Cache) but IR passes sank the plain
// loads past sched_barrier -> 4-deep serialized (VGPR 72) -> 81 us.
// R11/R12: asm-load batches corrupt — allocator inserts v_mov copies that
// read in-flight load dests (asm assumed synchronous); absmax 3e16 / 468.
// Raw asm loads abandoned.
//
// R13: VOLATILE caching loads. (1) Correct by construction: volatile loads
// are compiler-tracked IR loads — precise vmcnt inserted before every use,
// spill, or copy. (2) Batch survives: volatile ops keep mutual order and
// cannot cross the side-effecting sched_barrier at IR or machine level ->
// R6's 32-deep burst shape is preserved to emission (VGPR_Count >= ~140
// verifies; ~72 = collapsed, void). (3) LLC still allocates: volatile may
// set scope bits (L2 bypass) but Infinity Cache is memory-side — only the
// nt bit suppresses allocation, and we don't set it on loads.
// Stores stay nt: the 134 MB output has zero reuse and must not evict x.
// Structure = exact R6; load qualifier is the only variable.

#define T_STEPS 4
#define UNROLL 8
#define BLOCK 256

typedef float vfloat4 __attribute__((ext_vector_type(4)));

__global__ __launch_bounds__(256) void IF_18622978195596_kernel(
    const vfloat4* __restrict__ x, const float* __restrict__ thresh_p,
    vfloat4* __restrict__ out, int n4) {
    // n4 = 2^21 divides exactly by BLOCK*UNROLL = 2048; no guards.
    const int base = blockIdx.x * (BLOCK * UNROLL) + threadIdx.x;
    const float th = *thresh_p;

    const volatile vfloat4* __restrict__ xv_ptr = x;

    // ---- load phase: 32 volatile caching loads, u-major (consume order).
    // Volatile pins order + keeps all 32 results live across the barrier;
    // compiler still owns the waitcnts (correctness-safe). ----
    vfloat4 xv[UNROLL][T_STEPS];
#pragma unroll
    for (int u = 0; u < UNROLL; ++u) {
        const int i = base + u * BLOCK;
#pragma unroll
        for (int t = 0; t < T_STEPS; ++t) {
            xv[u][t] = xv_ptr[(size_t)t * n4 + i];
        }
    }
    // pin the phase boundary: nothing crosses this point
    __builtin_amdgcn_sched_barrier(0);

    // ---- consume phase, in issue order -> progressive vmcnt drain ----
#pragma unroll
    for (int u = 0; u < UNROLL; ++u) {
        const int i = base + u * BLOCK;
        vfloat4 mem = {0.5f * th, 0.5f * th, 0.5f * th, 0.5f * th};
#pragma unroll
        for (int t = 0; t < T_STEPS; ++t) {
            mem += xv[u][t];
            vfloat4 s;
            s.x = (mem.x >= th) ? th : 0.0f;
            s.y = (mem.y >= th) ? th : 0.0f;
            s.z = (mem.z >= th) ? th : 0.0f;
            s.w = (mem.w >= th) ? th : 0.0f;
            mem -= s;
            // nt store: output has zero reuse; must not evict x from LLC.
            __builtin_nontemporal_store(s, &out[(size_t)t * n4 + i]);
        }
    }
}

extern "C" void kernel_launch(void* const* d_in, const int* in_sizes, int n_in,
                              void* d_out, int out_size, void* d_ws,
                              size_t ws_size, hipStream_t stream) {
    const float* x = (const float*)d_in[0];
    const float* thresh = (const float*)d_in[1];
    float* out = (float*)d_out;

    int total = in_sizes[0];              // 33,554,432 floats
    int n_per_t = total / T_STEPS;        // 8,388,608 neurons
    int n4 = n_per_t / 4;                 // 2,097,152 vfloat4 per timestep

    int block = BLOCK;
    int per_block = block * UNROLL;       // 2048 vfloat4 per block per t
    int grid = n4 / per_block;            // 1024 blocks = 4 per CU, exact
    IF_18622978195596_kernel<<<grid, block, 0, stream>>>(
        (const vfloat4*)x, thresh, (vfloat4*)out, n4);
}

// Round 9
// 237.441 us; speedup vs baseline: 1.0213x; 1.0213x over previous
//
#include <hip/hip_runtime.h>

// SNN IF scan, T=4. Memory-bound: 134 MB in + 134 MB out. Ladder:
// serialized nt = ~82 us; R6 32-deep nt u-major burst = ~62 (passing
// baseline); R7/R8/R9 schedule variants null at ~62. Caching-load history:
// R10 plain loads -> FETCH halved (67 MB of x served from the 256 MiB
// memory-side LLC) but IR sank the batch (VGPR 72, 81 us). R11/R12 asm
// loads -> allocator copies race in-flight data (absmax 3e16/468). R13
// volatile loads -> legalizer vmcnt(0) after every load (88 us), FETCH
// halved again. Root cause: caching loads WITH VGPR destinations leave
// batch depth to compiler passes.
//
// R14/R15: global_load_lds — the one load path with NO VGPR destination.
// Async, vmcnt-counted, side-effecting (cannot be sunk or collapsed),
// aux=0 = CACHING. Per wave: D=3-slot private LDS ring, slot = one
// u-step's 4 planes (4x 1KB; wave-uniform LDS dest + HW lane*16; global
// src per-lane contiguous). Iteration j: derived wait vmcnt(W_j) ->
// ds_read x4 -> lgkmcnt(0) (slot reusable) -> ISSUE(j+3) -> compute ->
// nt stores (output must not evict x from LLC). NO barriers of any kind
// -> no deadlock possible, no barrier drain. LDS 48 KB -> 3 blocks/CU =
// 12 waves/CU (R6 occupancy). Rule-#18 fences only (memory clobber +
// sched_barrier); no operand ties (R11 lesson).
// W table (op enumeration: L0 L1 L2 | w L3 S0 | w L4 S1 | ...):
//   j : 0  1  2  3  4  5  6  7
//   W : 8 12 16 20 20 20 16 12
// Compiler-added waits / split stores only tighten (safe direction).
// R15 = R14 + explicit readfirstlane on 'wave' (LDS dest provably
// uniform — kills any waterfall-expansion risk). R14's bench died to a
// container-level infra failure (no pytest/compile output); kernel has no
// hang mechanism (zero barriers, all waits monotonically satisfiable).
// Verify: FETCH ~65.5e3 KB, WRITE ~131e3 KB; VGPR small (~48) — depth
// lives in the vmcnt domain now, proven by dur+FETCH, not VGPR.

#define T_STEPS 4
#define NB 8   // u-steps per thread
#define D 3    // ring slots
#define BLOCK 256

typedef float vfloat4 __attribute__((ext_vector_type(4)));

__global__ __launch_bounds__(256) void IF_18622978195596_kernel(
    const vfloat4* __restrict__ x, const float* __restrict__ thresh_p,
    vfloat4* __restrict__ out, int n4) {
    // [slot][wave][t][lane] : 3*4*4*64 vfloat4 = 48 KB
    __shared__ vfloat4 lds[D * 4 * T_STEPS * 64];

    const int tid = threadIdx.x;
    // Explicitly uniform wave id: readfirstlane puts it in an SGPR so the
    // LDS destination of global_load_lds is provably wave-uniform.
    const int wave = __builtin_amdgcn_readfirstlane(tid >> 6);  // 0..3
    const int lane = tid & 63;
    // n4 = 2^21 divides exactly by BLOCK*NB = 2048; no guards.
    const int base = blockIdx.x * (BLOCK * NB) + tid;
    const float th = *thresh_p;

// 4 caching async loads for u-step j into ring slot j%D. LDS dest is
// wave-uniform (no lane term); HW adds lane*16. Global addr is per-lane.
#define ISSUE(j)                                                             \
    {                                                                        \
        _Pragma("unroll")                                                    \
        for (int t = 0; t < T_STEPS; ++t) {                                  \
            const vfloat4* gp_ = &x[(size_t)t * n4 + base + (j) * BLOCK];    \
            vfloat4* lp_ = &lds[((((j) % D) * 4 + wave) * T_STEPS + t) * 64];\
            __builtin_amdgcn_global_load_lds(                                \
                (const __attribute__((address_space(1))) void*)gp_,          \
                (__attribute__((address_space(3))) void*)lp_, 16, 0, 0);     \
        }                                                                    \
        __builtin_amdgcn_sched_barrier(0); /* pin L-before-S order */        \
    }

#define SPK(VT, t)                                                           \
    mem += VT;                                                               \
    s.x = (mem.x >= th) ? th : 0.0f;                                         \
    s.y = (mem.y >= th) ? th : 0.0f;                                         \
    s.z = (mem.z >= th) ? th : 0.0f;                                         \
    s.w = (mem.w >= th) ? th : 0.0f;                                         \
    mem -= s;                                                                \
    __builtin_nontemporal_store(s, &out[(size_t)(t) * n4 + i_]);

#define STEP(j, WSTR)                                                        \
    {                                                                        \
        asm volatile("s_waitcnt vmcnt(" WSTR ")" ::: "memory");              \
        __builtin_amdgcn_sched_barrier(0);                                   \
        const int sb_ = (((j) % D) * 4 + wave) * T_STEPS;                    \
        vfloat4 v0 = lds[(sb_ + 0) * 64 + lane];                             \
        vfloat4 v1 = lds[(sb_ + 1) * 64 + lane];                             \
        vfloat4 v2 = lds[(sb_ + 2) * 64 + lane];                             \
        vfloat4 v3 = lds[(sb_ + 3) * 64 + lane];                             \
        asm volatile("s_waitcnt lgkmcnt(0)" ::: "memory");                   \
        __builtin_amdgcn_sched_barrier(0); /* slot now safe to overwrite */  \
        if ((j) + D < NB) ISSUE((j) + D);                                    \
        const int i_ = base + (j) * BLOCK;                                   \
        vfloat4 mem = {0.5f * th, 0.5f * th, 0.5f * th, 0.5f * th};          \
        vfloat4 s;                                                           \
        SPK(v0, 0) SPK(v1, 1) SPK(v2, 2) SPK(v3, 3)                          \
    }

    // prologue: fill the ring (12 loads in flight)
    ISSUE(0) ISSUE(1) ISSUE(2)

    // derived waits: W_j = #VMEM ops issued after slot j's last load
    STEP(0, "8")  STEP(1, "12") STEP(2, "16") STEP(3, "20")
    STEP(4, "20") STEP(5, "20") STEP(6, "16") STEP(7, "12")

#undef ISSUE
#undef SPK
#undef STEP
}

extern "C" void kernel_launch(void* const* d_in, const int* in_sizes, int n_in,
                              void* d_out, int out_size, void* d_ws,
                              size_t ws_size, hipStream_t stream) {
    const float* x = (const float*)d_in[0];
    const float* thresh = (const float*)d_in[1];
    float* out = (float*)d_out;

    int total = in_sizes[0];              // 33,554,432 floats
    int n_per_t = total / T_STEPS;        // 8,388,608 neurons
    int n4 = n_per_t / 4;                 // 2,097,152 vfloat4 per timestep

    int per_block = BLOCK * NB;           // 2048 vfloat4 per block per t
    int grid = n4 / per_block;            // 1024 blocks
    IF_18622978195596_kernel<<<grid, BLOCK, 0, stream>>>(
        (const vfloat4*)x, thresh, (vfloat4*)out, n4);
}